// Round 4
// baseline (10.433 us; speedup 1.0000x reference)
//
#include <hip/hip_runtime.h>
#include <math.h>

#define H 128

__device__ __forceinline__ float wave_reduce_sum(float v) {
    // full 64-lane wavefront reduction (CDNA wave = 64, not 32)
    #pragma unroll
    for (int m = 32; m >= 1; m >>= 1) v += __shfl_xor(v, m, 64);
    return v;
}

__device__ __forceinline__ float sigmoidf_(float x) {
    return 1.0f / (1.0f + __expf(-x));
}

__device__ __forceinline__ float tanhf_fast(float x) {
    // tanh(x) = 2*sigmoid(2x) - 1, via v_exp_f32 (no ocml libcall)
    const float e = __expf(-2.0f * x);
    return (1.0f - e) / (1.0f + e);
}

// One block per output element j (128 blocks), 4 waves per block.
// r and z gates sum x-part and h-part BEFORE the activation, so their
// per-lane partials are combined pre-reduction -> one 6-step chain each:
//   wave 0: r   = w_ih[j]     . x + w_hh[j]     . h   (combined)
//   wave 1: z   = w_ih[j+128] . x + w_hh[j+128] . h   (combined)
//   wave 2: n_x = w_ih[j+256] . x                     (needed separate)
//   wave 3: n_h = w_hh[j+256] . h                     (needed separate)
// Every wave runs exactly ONE 6-step butterfly; biases folded pre-LDS;
// tail is 4 LDS reads -> sigmoid/sigmoid/fast-tanh -> store.
__global__ __launch_bounds__(256) void gru_fwd_cell_kernel(
    const float* __restrict__ x,      // (512,)
    const float* __restrict__ h0,     // (2,1,128) -> forward dir = h0[0..127]
    const float* __restrict__ w_ih,   // (384,512) row-major
    const float* __restrict__ w_hh,   // (384,128) row-major
    const float* __restrict__ b_ih,   // (384,)
    const float* __restrict__ b_hh,   // (384,)
    float* __restrict__ out)          // (128,)
{
    const int j    = blockIdx.x;        // output index 0..127
    const int tid  = threadIdx.x;       // 0..255
    const int wave = tid >> 6;          // 0..3
    const int lane = tid & 63;          // 0..63

    const float4* x4 = reinterpret_cast<const float4*>(x);
    const float2* h2 = reinterpret_cast<const float2*>(h0);  // forward dir

    // wave-uniform, issued at top, latency hidden
    const float hj = h0[j];

    float acc  = 0.0f;
    float bias = 0.0f;

    if (wave < 2) {
        // r (wave 0) / z (wave 1): combined X+H dot, biases folded.
        const int row = j + (wave << 7);
        const float4* w4  = reinterpret_cast<const float4*>(w_ih + (size_t)row * 512);
        const float2* wh2 = reinterpret_cast<const float2*>(w_hh + (size_t)row * H);
        const float4 wa = w4[lane];
        const float4 wb = w4[lane + 64];
        const float2 wh = wh2[lane];
        const float4 xa = x4[lane];
        const float4 xb = x4[lane + 64];
        const float2 hv = h2[lane];
        acc = wa.x * xa.x + wa.y * xa.y + wa.z * xa.z + wa.w * xa.w
            + wb.x * xb.x + wb.y * xb.y + wb.z * xb.z + wb.w * xb.w
            + wh.x * hv.x + wh.y * hv.y;
        bias = b_ih[row] + b_hh[row];
    } else if (wave == 2) {
        // n_x = w_ih[j+256] . x
        const int row = j + 256;
        const float4* w4 = reinterpret_cast<const float4*>(w_ih + (size_t)row * 512);
        const float4 wa = w4[lane];
        const float4 wb = w4[lane + 64];
        const float4 xa = x4[lane];
        const float4 xb = x4[lane + 64];
        acc = wa.x * xa.x + wa.y * xa.y + wa.z * xa.z + wa.w * xa.w
            + wb.x * xb.x + wb.y * xb.y + wb.z * xb.z + wb.w * xb.w;
        bias = b_ih[row];
    } else {
        // n_h = w_hh[j+256] . h  (tiny load, fastest wave)
        const int row = j + 256;
        const float2* wh2 = reinterpret_cast<const float2*>(w_hh + (size_t)row * H);
        const float2 wh = wh2[lane];
        const float2 hv = h2[lane];
        acc = wh.x * hv.x + wh.y * hv.y;
        bias = b_hh[row];
    }

    acc = wave_reduce_sum(acc);

    __shared__ float s[4];
    if (lane == 0) s[wave] = acc + bias;
    __syncthreads();

    if (tid == 0) {
        const float r = sigmoidf_(s[0]);
        const float z = sigmoidf_(s[1]);
        const float n = tanhf_fast(s[2] + r * s[3]);
        out[j] = (1.0f - z) * n + z * hj;
    }
}

extern "C" void kernel_launch(void* const* d_in, const int* in_sizes, int n_in,
                              void* d_out, int out_size, void* d_ws, size_t ws_size,
                              hipStream_t stream) {
    const float* x    = (const float*)d_in[0];   // (1,512)
    const float* h0   = (const float*)d_in[1];   // (2,1,128)
    const float* w_ih = (const float*)d_in[2];   // (384,512)
    const float* w_hh = (const float*)d_in[3];   // (384,128)
    const float* b_ih = (const float*)d_in[4];   // (384,)
    const float* b_hh = (const float*)d_in[5];   // (384,)
    float* out = (float*)d_out;                  // (1,128)

    gru_fwd_cell_kernel<<<H, 256, 0, stream>>>(x, h0, w_ih, w_hh, b_ih, b_hh, out);
}